// Round 1
// baseline (258.601 us; speedup 1.0000x reference)
//
#include <hip/hip_runtime.h>
#include <hip/hip_bf16.h>
#include <cstdio>
#include <cstdint>

// Problem constants (B=2, S=4096, D=1024, E=8, K=2)
static constexpr int TOK = 8192;    // B*S tokens
static constexpr int DIM = 1024;    // model dim (in = out)
static constexpr int NEXP = 8;
static constexpr int TOPK = 2;

typedef unsigned short u16;
typedef unsigned int u32;

using floatx4 = __attribute__((ext_vector_type(4))) float;
using bf16x8  = __attribute__((ext_vector_type(8))) __bf16;

// ---------- helpers ----------
__device__ __forceinline__ u16 f2bf(float f) {
  union { float f; u32 u; } v; v.f = f;
  u32 r = v.u + 0x7fffu + ((v.u >> 16) & 1u);   // RNE
  return (u16)(r >> 16);
}

__device__ __forceinline__ void gload_lds16(const void* g, void* l) {
  __builtin_amdgcn_global_load_lds(
      (const __attribute__((address_space(1))) void*)g,
      (__attribute__((address_space(3))) void*)l,
      16, 0, 0);
}

// ---------- bookkeeping ----------
__global__ void zero_meta_kernel(int* meta) {
  if (threadIdx.x < 48) meta[threadIdx.x] = 0;
}

__global__ void count_kernel(const int* __restrict__ idx, int* __restrict__ counts) {
  int g = blockIdx.x * 256 + threadIdx.x;      // 0..16383 = (token, k)
  int k = g & 1;
  int e = idx[g];
  atomicAdd(&counts[k * NEXP + e], 1);
}

__global__ void scan_kernel(const int* __restrict__ counts, int* __restrict__ offsets,
                            int* __restrict__ cursors) {
  if (threadIdx.x == 0) {
    for (int k = 0; k < TOPK; ++k) {
      int run = 0;
      for (int e = 0; e < NEXP; ++e) {
        offsets[k * NEXP + e] = run;
        cursors[k * NEXP + e] = run;
        run += counts[k * NEXP + e];
      }
    }
  }
}

__global__ void scatter_kernel(const int* __restrict__ idx, const float* __restrict__ ew,
                               int* __restrict__ cursors, int* __restrict__ tokList,
                               float* __restrict__ wList) {
  int g = blockIdx.x * 256 + threadIdx.x;      // (token, k)
  int k = g & 1, t = g >> 1;
  int e = idx[g];
  int pos = atomicAdd(&cursors[k * NEXP + e], 1);
  tokList[k * TOK + pos] = t;
  wList[k * TOK + pos] = ew[g];
}

// ---------- conversions ----------
__global__ void convert_x_kernel(const float* __restrict__ x, u16* __restrict__ xb) {
  size_t i = (size_t)blockIdx.x * 256 + threadIdx.x;   // one 8-elem chunk
  const float4* s = reinterpret_cast<const float4*>(x) + 2 * i;
  float4 a = s[0], b = s[1];
  uint4 o;
  o.x = (u32)f2bf(a.x) | ((u32)f2bf(a.y) << 16);
  o.y = (u32)f2bf(a.z) | ((u32)f2bf(a.w) << 16);
  o.z = (u32)f2bf(b.x) | ((u32)f2bf(b.y) << 16);
  o.w = (u32)f2bf(b.z) | ((u32)f2bf(b.w) << 16);
  reinterpret_cast<uint4*>(xb)[i] = o;
}

// W[e][d][f] fp32 -> Wt[e][f][d] bf16 (LDS-tiled transpose, coalesced both sides)
__global__ void transpose_w_kernel(const float* __restrict__ W, u16* __restrict__ wt) {
  __shared__ u16 tile[32][33];
  const int e = blockIdx.z;
  const int f0 = blockIdx.x * 32, d0 = blockIdx.y * 32;
  const float* src = W + ((size_t)e << 20);
  u16* dst = wt + ((size_t)e << 20);
  const int tx = threadIdx.x, ty = threadIdx.y;   // 32 x 8
#pragma unroll
  for (int j = 0; j < 4; ++j) {
    int d = d0 + ty + 8 * j;
    tile[ty + 8 * j][tx] = f2bf(src[(size_t)d * DIM + f0 + tx]);
  }
  __syncthreads();
#pragma unroll
  for (int j = 0; j < 4; ++j) {
    int f = f0 + ty + 8 * j;
    dst[(size_t)f * DIM + d0 + tx] = tile[tx][ty + 8 * j];
  }
}

// ---------- grouped GEMM ----------
// Per (pass k, expert e): C[p][f] = w_p * (x[tok_p] . W[e][:,f] + b[e][f])
// ACCUM=0: store (pass k=0 covers every token exactly once)
// ACCUM=1: out += (pass k=1)
template <int ACCUM>
__global__ __launch_bounds__(256)
void moe_gemm_kernel(const u16* __restrict__ xb, const u16* __restrict__ wt,
                     const float* __restrict__ bias, const int* __restrict__ tokList,
                     const float* __restrict__ wList, const int* __restrict__ counts,
                     const int* __restrict__ offsets, float* __restrict__ out) {
  constexpr int BM = 128, BN = 128, BK = 64;
  const int e = blockIdx.z;
  const int g = ACCUM * NEXP + e;
  const int n = counts[g];
  const int mt = blockIdx.y;
  if (mt * BM >= n) return;
  const int nt = blockIdx.x;

  __shared__ __align__(16) u16 As[BM * BK];   // [m][k] 16KB
  __shared__ __align__(16) u16 Bs[BN * BK];   // [n][k] 16KB (Wt rows are k-contiguous)
  __shared__ int   tokS[BM];
  __shared__ float wS[BM];

  const int tid = threadIdx.x;
  const int listBase = ACCUM * TOK + offsets[g];

  if (tid < BM) {
    int p = mt * BM + tid;
    int pc = p < n ? p : (n - 1);     // clamp ragged tail (masked on store)
    tokS[tid] = tokList[listBase + pc];
    wS[tid]   = wList[listBase + pc];
  }
  __syncthreads();

  const int rowA  = tid >> 3;   // 0..31: LDS row this thread stages (stride 32)
  const int chunk = tid & 7;    // 16B chunk within a 128B row
  int tokR[4];
#pragma unroll
  for (int i = 0; i < 4; ++i) tokR[i] = tokS[rowA + 32 * i];

  const u16* wb = wt + ((size_t)e << 20);
  const int wid = tid >> 6, lane = tid & 63;
  const int wm = (wid >> 1) * 64, wn = (wid & 1) * 64;   // 2x2 waves, 64x64 each
  const int lr = lane & 15, lg = lane >> 4;

  floatx4 acc[4][4];
#pragma unroll
  for (int i = 0; i < 4; ++i)
#pragma unroll
    for (int j = 0; j < 4; ++j) acc[i][j] = (floatx4){0.f, 0.f, 0.f, 0.f};

  for (int kt = 0; kt < DIM / BK; ++kt) {
    __syncthreads();                      // previous tile fully consumed
#pragma unroll
    for (int i = 0; i < 4; ++i) {         // A: gathered token rows
      const u16* s = xb + ((size_t)tokR[i] << 10) + kt * BK + chunk * 8;
      gload_lds16(s, &As[(rowA + 32 * i) * BK + chunk * 8]);
    }
#pragma unroll
    for (int i = 0; i < 4; ++i) {         // B: Wt rows (f-major, d-contiguous)
      const u16* s = wb + ((size_t)(nt * BN + rowA + 32 * i) << 10) + kt * BK + chunk * 8;
      gload_lds16(s, &Bs[(rowA + 32 * i) * BK + chunk * 8]);
    }
    asm volatile("s_waitcnt vmcnt(0)" ::: "memory");
    __syncthreads();

#pragma unroll
    for (int ks = 0; ks < 2; ++ks) {      // two K=32 sub-steps
      bf16x8 av[4], bv[4];
#pragma unroll
      for (int mi = 0; mi < 4; ++mi)
        av[mi] = *reinterpret_cast<const bf16x8*>(&As[(wm + mi * 16 + lr) * BK + ks * 32 + lg * 8]);
#pragma unroll
      for (int ni = 0; ni < 4; ++ni)
        bv[ni] = *reinterpret_cast<const bf16x8*>(&Bs[(wn + ni * 16 + lr) * BK + ks * 32 + lg * 8]);
#pragma unroll
      for (int mi = 0; mi < 4; ++mi)
#pragma unroll
        for (int ni = 0; ni < 4; ++ni)
          acc[mi][ni] = __builtin_amdgcn_mfma_f32_16x16x32_bf16(av[mi], bv[ni], acc[mi][ni], 0, 0, 0);
    }
  }

  // epilogue: D[row=(lane>>4)*4+r][col=lane&15] per 16x16 frag (m89-verified layout)
  const float* bp = bias + e * DIM;
#pragma unroll
  for (int mi = 0; mi < 4; ++mi) {
    const int rl0 = wm + mi * 16 + lg * 4;
#pragma unroll
    for (int ni = 0; ni < 4; ++ni) {
      const int col = nt * BN + wn + ni * 16 + lr;
      const float bv = bp[col];
#pragma unroll
      for (int r = 0; r < 4; ++r) {
        const int rl = rl0 + r;
        if (mt * BM + rl < n) {
          const float v = wS[rl] * (acc[mi][ni][r] + bv);
          float* o = out + ((size_t)tokS[rl] << 10) + col;
          if (ACCUM) *o += v; else *o = v;
        }
      }
    }
  }
}

// ---------- host ----------
extern "C" void kernel_launch(void* const* d_in, const int* in_sizes, int n_in,
                              void* d_out, int out_size, void* d_ws, size_t ws_size,
                              hipStream_t stream) {
  const float* x    = (const float*)d_in[0];   // [2,4096,1024] f32
  const float* ew   = (const float*)d_in[1];   // [2,4096,2]    f32
  const int*   idx  = (const int*)d_in[2];     // [2,4096,2]    i32
  const float* W    = (const float*)d_in[3];   // [8,1024,1024] f32
  const float* bias = (const float*)d_in[4];   // [8,1024]      f32
  float* out = (float*)d_out;                  // [2,4096,1024] f32

  char* ws = (char*)d_ws;
  u16*   xb      = (u16*)ws;                                   // 16 MB bf16 x
  u16*   wtp     = (u16*)(ws + (size_t)(16 << 20));            // 16 MB bf16 W^T
  int*   tokList = (int*)(ws + (size_t)(32 << 20));            // 64 KB
  float* wList   = (float*)(ws + (size_t)(32 << 20) + (64 << 10)); // 64 KB
  int*   meta    = (int*)(ws + (size_t)(32 << 20) + (128 << 10));  // 48 ints
  const size_t need = (size_t)(32 << 20) + (128 << 10) + 192;
  if (ws_size < need) {
    fprintf(stderr, "kernel_launch: ws_size %zu < needed %zu\n", ws_size, need);
    return;
  }
  int* counts = meta, *offsets = meta + 16, *cursors = meta + 32;

  zero_meta_kernel<<<1, 64, 0, stream>>>(meta);
  count_kernel<<<64, 256, 0, stream>>>(idx, counts);
  scan_kernel<<<1, 1, 0, stream>>>(counts, offsets, cursors);
  scatter_kernel<<<64, 256, 0, stream>>>(idx, ew, cursors, tokList, wList);
  convert_x_kernel<<<4096, 256, 0, stream>>>(x, xb);
  transpose_w_kernel<<<dim3(32, 32, 8), dim3(32, 8), 0, stream>>>(W, wtp);

  dim3 gg(DIM / 128, TOK / 128, NEXP);  // nt, max mt, expert
  moe_gemm_kernel<0><<<gg, 256, 0, stream>>>(xb, wtp, bias, tokList, wList, counts, offsets, out);
  moe_gemm_kernel<1><<<gg, 256, 0, stream>>>(xb, wtp, bias, tokList, wList, counts, offsets, out);
}

// Round 2
// 224.256 us; speedup vs baseline: 1.1532x; 1.1532x over previous
//
#include <hip/hip_runtime.h>
#include <hip/hip_bf16.h>
#include <cstdio>
#include <cstdint>

// Problem constants (B=2, S=4096, D=1024, E=8, K=2)
static constexpr int TOK = 8192;    // B*S tokens
static constexpr int DIM = 1024;    // model dim (in = out)
static constexpr int NEXP = 8;
static constexpr int NGRP = 16;     // (k, expert) groups

typedef unsigned short u16;
typedef unsigned int u32;

using floatx4 = __attribute__((ext_vector_type(4))) float;
using bf16x8  = __attribute__((ext_vector_type(8))) __bf16;

// meta layout (ints): [0..15] counts, [16..31] offsets, [32..47] cursors,
//                     [48] numTiles total, [49] numTiles for k=0 groups
// tileMap: up to 144 ints, (g<<12)|m0

// ---------- helpers ----------
__device__ __forceinline__ u16 f2bf(float f) {
  union { float f; u32 u; } v; v.f = f;
  u32 r = v.u + 0x7fffu + ((v.u >> 16) & 1u);   // RNE
  return (u16)(r >> 16);
}

__device__ __forceinline__ void gload_lds16(const void* g, void* l) {
  __builtin_amdgcn_global_load_lds(
      (const __attribute__((address_space(1))) void*)g,
      (__attribute__((address_space(3))) void*)l,
      16, 0, 0);
}

// ---------- bookkeeping ----------
__global__ void init_meta_kernel(int* meta) {
  if (threadIdx.x < 64) meta[threadIdx.x] = 0;
}

__global__ void count_kernel(const int* __restrict__ idx, int* __restrict__ meta) {
  int i = blockIdx.x * 256 + threadIdx.x;      // 0..16383 = (token, k)
  int k = i & 1;
  int e = idx[i];
  atomicAdd(&meta[k * NEXP + e], 1);
}

__global__ void scan_kernel(int* __restrict__ meta, int* __restrict__ tileMap) {
  if (threadIdx.x == 0) {
    int run = 0, t = 0, tk0 = 0;
    for (int g = 0; g < NGRP; ++g) {
      meta[16 + g] = run;   // offset
      meta[32 + g] = run;   // cursor
      int n = meta[g];
      int nt = (n + 127) >> 7;
      for (int m0 = 0; m0 < nt; ++m0) tileMap[t++] = (g << 12) | m0;
      if (g == NEXP - 1) tk0 = t;
      run += n;
    }
    meta[48] = t;
    meta[49] = tk0;
  }
}

__global__ void scatter_kernel(const int* __restrict__ idx, const float* __restrict__ ew,
                               int* __restrict__ meta, int* __restrict__ tokList,
                               float* __restrict__ wList) {
  int i = blockIdx.x * 256 + threadIdx.x;      // (token, k)
  int k = i & 1, t = i >> 1;
  int e = idx[i];
  int g = k * NEXP + e;
  int pos = atomicAdd(&meta[32 + g], 1);
  tokList[pos] = t;
  wList[pos] = ew[i];
}

// ---------- conversions ----------
__global__ void convert_x_kernel(const float* __restrict__ x, u16* __restrict__ xb) {
  size_t i = (size_t)blockIdx.x * 256 + threadIdx.x;   // one 8-elem chunk
  const float4* s = reinterpret_cast<const float4*>(x) + 2 * i;
  float4 a = s[0], b = s[1];
  uint4 o;
  o.x = (u32)f2bf(a.x) | ((u32)f2bf(a.y) << 16);
  o.y = (u32)f2bf(a.z) | ((u32)f2bf(a.w) << 16);
  o.z = (u32)f2bf(b.x) | ((u32)f2bf(b.y) << 16);
  o.w = (u32)f2bf(b.z) | ((u32)f2bf(b.w) << 16);
  reinterpret_cast<uint4*>(xb)[i] = o;
}

// W[e][d][f] fp32 -> Wt[e][f][d] bf16 (LDS-tiled transpose)
__global__ void transpose_w_kernel(const float* __restrict__ W, u16* __restrict__ wt) {
  __shared__ u16 tile[32][33];
  const int e = blockIdx.z;
  const int f0 = blockIdx.x * 32, d0 = blockIdx.y * 32;
  const float* src = W + ((size_t)e << 20);
  u16* dst = wt + ((size_t)e << 20);
  const int tx = threadIdx.x, ty = threadIdx.y;   // 32 x 8
#pragma unroll
  for (int j = 0; j < 4; ++j) {
    int d = d0 + ty + 8 * j;
    tile[ty + 8 * j][tx] = f2bf(src[(size_t)d * DIM + f0 + tx]);
  }
  __syncthreads();
#pragma unroll
  for (int j = 0; j < 4; ++j) {
    int f = f0 + ty + 8 * j;
    dst[(size_t)f * DIM + d0 + tx] = tile[tx][ty + 8 * j];
  }
}

// ---------- fused grouped GEMM ----------
// pass = -1 : single dispatch over all 16 groups. k=0 groups store to out,
//             k=1 groups store to cbuf (combined later). No RMW, no atomics.
// pass = 0  : groups 0..7 (tiles [0, meta[49])), plain store to out.
// pass = 1  : groups 8..15 (tiles [meta[49], meta[48])), out += (RMW).
__global__ __launch_bounds__(256)
void moe_gemm_kernel(const u16* __restrict__ xb, const u16* __restrict__ wt,
                     const float* __restrict__ bias, const int* __restrict__ tokList,
                     const float* __restrict__ wList, const int* __restrict__ meta,
                     const int* __restrict__ tileMap, float* __restrict__ out,
                     float* __restrict__ cbuf, int pass) {
  constexpr int BM = 128, BN = 128, BK = 64;
  // XCD-bijective swizzle: nwg = gridDim.y*8 (divisible by 8 by construction)
  const int chunk = gridDim.y;                 // nwg / 8
  int lin = blockIdx.y * 8 + blockIdx.x;
  int swz = (lin & 7) * chunk + (lin >> 3);
  int tileIdx = swz >> 3, nt = swz & 7;

  int tBase = 0, tEnd = meta[48];
  const int tilesK0 = meta[49];
  if (pass == 0) tEnd = tilesK0;
  else if (pass == 1) tBase = tilesK0;
  tileIdx += tBase;
  if (tileIdx >= tEnd) return;

  const int tm = tileMap[tileIdx];
  const int g = tm >> 12, m0 = tm & 0xfff;
  const int e = g & (NEXP - 1);
  const int nrem = meta[g] - m0 * BM;          // rows remaining in this group (>0)
  const int listBase = meta[16 + g] + m0 * BM;

  __shared__ __align__(16) u16 As[BM * BK];    // [m][k] 16KB
  __shared__ __align__(16) u16 Bs[BN * BK];    // [n][k] 16KB
  __shared__ int   tokS[BM];
  __shared__ float wS[BM];

  const int tid = threadIdx.x;
  if (tid < BM) {
    int pc = tid < nrem ? tid : (nrem - 1);    // clamp ragged tail (masked on store)
    tokS[tid] = tokList[listBase + pc];
    wS[tid]   = wList[listBase + pc];
  }
  __syncthreads();

  const int rowA  = tid >> 3;   // 0..31: LDS row this thread stages (stride 32)
  const int chnk  = tid & 7;    // 16B chunk within a 128B row
  int tokR[4];
#pragma unroll
  for (int i = 0; i < 4; ++i) tokR[i] = tokS[rowA + 32 * i];

  const u16* wb = wt + ((size_t)e << 20);
  const int wid = tid >> 6, lane = tid & 63;
  const int wm = (wid >> 1) * 64, wn = (wid & 1) * 64;   // 2x2 waves, 64x64 each
  const int lr = lane & 15, lg = lane >> 4;

  floatx4 acc[4][4];
#pragma unroll
  for (int i = 0; i < 4; ++i)
#pragma unroll
    for (int j = 0; j < 4; ++j) acc[i][j] = (floatx4){0.f, 0.f, 0.f, 0.f};

  for (int kt = 0; kt < DIM / BK; ++kt) {
    __syncthreads();                      // previous tile fully consumed
#pragma unroll
    for (int i = 0; i < 4; ++i) {         // A: gathered token rows
      const u16* s = xb + ((size_t)tokR[i] << 10) + kt * BK + chnk * 8;
      gload_lds16(s, &As[(rowA + 32 * i) * BK + chnk * 8]);
    }
#pragma unroll
    for (int i = 0; i < 4; ++i) {         // B: Wt rows (f-major, d-contiguous)
      const u16* s = wb + ((size_t)(nt * BN + rowA + 32 * i) << 10) + kt * BK + chnk * 8;
      gload_lds16(s, &Bs[(rowA + 32 * i) * BK + chnk * 8]);
    }
    asm volatile("s_waitcnt vmcnt(0)" ::: "memory");
    __syncthreads();

#pragma unroll
    for (int ks = 0; ks < 2; ++ks) {      // two K=32 sub-steps
      bf16x8 av[4], bv[4];
#pragma unroll
      for (int mi = 0; mi < 4; ++mi)
        av[mi] = *reinterpret_cast<const bf16x8*>(&As[(wm + mi * 16 + lr) * BK + ks * 32 + lg * 8]);
#pragma unroll
      for (int ni = 0; ni < 4; ++ni)
        bv[ni] = *reinterpret_cast<const bf16x8*>(&Bs[(wn + ni * 16 + lr) * BK + ks * 32 + lg * 8]);
#pragma unroll
      for (int mi = 0; mi < 4; ++mi)
#pragma unroll
        for (int ni = 0; ni < 4; ++ni)
          acc[mi][ni] = __builtin_amdgcn_mfma_f32_16x16x32_bf16(av[mi], bv[ni], acc[mi][ni], 0, 0, 0);
    }
  }

  // epilogue: D[row=(lane>>4)*4+r][col=lane&15] per 16x16 frag
  float* dst = (pass >= 0 || g < NEXP) ? out : cbuf;
  const bool rmw = (pass == 1);
  const float* bp = bias + e * DIM;
#pragma unroll
  for (int mi = 0; mi < 4; ++mi) {
    const int rl0 = wm + mi * 16 + lg * 4;
#pragma unroll
    for (int ni = 0; ni < 4; ++ni) {
      const int col = nt * BN + wn + ni * 16 + lr;
      const float bv = bp[col];
#pragma unroll
      for (int r = 0; r < 4; ++r) {
        const int rl = rl0 + r;
        if (rl < nrem) {
          const float v = wS[rl] * (acc[mi][ni][r] + bv);
          float* o = dst + ((size_t)tokS[rl] << 10) + col;
          if (rmw) *o += v; else *o = v;
        }
      }
    }
  }
}

// out += cbuf (mode A only). 8.4M floats = 2.1M float4.
__global__ void combine_kernel(float* __restrict__ out, const float* __restrict__ cbuf) {
  constexpr int TOTAL4 = TOK * DIM / 4;
  int i = blockIdx.x * 256 + threadIdx.x;
#pragma unroll
  for (int j = 0; j < 4; ++j) {
    int p = i + j * (TOTAL4 / 4);
    float4 a = reinterpret_cast<float4*>(out)[p];
    float4 b = reinterpret_cast<const float4*>(cbuf)[p];
    a.x += b.x; a.y += b.y; a.z += b.z; a.w += b.w;
    reinterpret_cast<float4*>(out)[p] = a;
  }
}

// ---------- host ----------
extern "C" void kernel_launch(void* const* d_in, const int* in_sizes, int n_in,
                              void* d_out, int out_size, void* d_ws, size_t ws_size,
                              hipStream_t stream) {
  const float* x    = (const float*)d_in[0];   // [2,4096,1024] f32
  const float* ew   = (const float*)d_in[1];   // [2,4096,2]    f32
  const int*   idx  = (const int*)d_in[2];     // [2,4096,2]    i32
  const float* W    = (const float*)d_in[3];   // [8,1024,1024] f32
  const float* bias = (const float*)d_in[4];   // [8,1024]      f32
  float* out = (float*)d_out;                  // [2,4096,1024] f32

  char* ws = (char*)d_ws;
  u16*   xb      = (u16*)ws;                                        // 16 MB
  u16*   wtp     = (u16*)(ws + (size_t)(16 << 20));                 // 16 MB
  int*   tokList = (int*)(ws + (size_t)(32 << 20));                 // 64 KB
  float* wList   = (float*)(ws + (size_t)(32 << 20) + (64 << 10));  // 64 KB
  int*   meta    = (int*)(ws + (size_t)(32 << 20) + (128 << 10));   // 64 ints
  int*   tileMap = (int*)(ws + (size_t)(32 << 20) + (129 << 10));   // 144 ints
  float* cbuf    = (float*)(ws + (size_t)(33 << 20));               // 32 MB (mode A)

  const size_t needB = (size_t)(33 << 20);                // without cbuf
  const size_t needA = (size_t)(65 << 20);                // with cbuf
  if (ws_size < needB) {
    fprintf(stderr, "kernel_launch: ws_size %zu < needed %zu\n", ws_size, needB);
    return;
  }
  const bool modeA = (ws_size >= needA);

  init_meta_kernel<<<1, 64, 0, stream>>>(meta);
  count_kernel<<<64, 256, 0, stream>>>(idx, meta);
  scan_kernel<<<1, 1, 0, stream>>>(meta, tileMap);
  scatter_kernel<<<64, 256, 0, stream>>>(idx, ew, meta, tokList, wList);
  convert_x_kernel<<<4096, 256, 0, stream>>>(x, xb);
  transpose_w_kernel<<<dim3(32, 32, 8), dim3(32, 8), 0, stream>>>(W, wtp);

  if (modeA) {
    // all 16 groups in one dispatch: max tiles = 16384/128 + 16 = 144
    moe_gemm_kernel<<<dim3(8, 144), 256, 0, stream>>>(
        xb, wtp, bias, tokList, wList, meta, tileMap, out, cbuf, -1);
    combine_kernel<<<TOK * DIM / 4 / 4 / 256, 256, 0, stream>>>(out, cbuf);
  } else {
    // two compact passes (max 72 tiles per k-slot; use 72 -> nwg=576, %8==0)
    moe_gemm_kernel<<<dim3(8, 72), 256, 0, stream>>>(
        xb, wtp, bias, tokList, wList, meta, tileMap, out, nullptr, 0);
    moe_gemm_kernel<<<dim3(8, 72), 256, 0, stream>>>(
        xb, wtp, bias, tokList, wList, meta, tileMap, out, nullptr, 1);
  }
}

// Round 3
// 160.542 us; speedup vs baseline: 1.6108x; 1.3969x over previous
//
#include <hip/hip_runtime.h>
#include <hip/hip_bf16.h>
#include <cstdio>
#include <cstdint>

// Problem constants (B=2, S=4096, D=1024, E=8, K=2)
static constexpr int TOK = 8192;    // B*S tokens
static constexpr int DIM = 1024;    // model dim (in = out)
static constexpr int NEXP = 8;
static constexpr int NGRP = 16;     // (k, expert) groups

typedef unsigned short u16;
typedef unsigned int u32;

using floatx4 = __attribute__((ext_vector_type(4))) float;
using bf16x8  = __attribute__((ext_vector_type(8))) __bf16;

// meta (ints): [0..15] counts, [16..31] offsets, [48] numTiles, [49] numTiles k=0
// tileMap: up to 144 ints, (g<<12)|m0

// ---------- helpers ----------
__device__ __forceinline__ u16 f2bf(float f) {
  union { float f; u32 u; } v; v.f = f;
  u32 r = v.u + 0x7fffu + ((v.u >> 16) & 1u);   // RNE
  return (u16)(r >> 16);
}

__device__ __forceinline__ void gload_lds16(const void* g, void* l) {
  __builtin_amdgcn_global_load_lds(
      (const __attribute__((address_space(1))) void*)g,
      (__attribute__((address_space(3))) void*)l,
      16, 0, 0);
}

// ---------- fused bookkeeping: count + scan + tileMap + scatter, one block ----------
__global__ __launch_bounds__(1024)
void prep_kernel(const int* __restrict__ idx, const float* __restrict__ ew,
                 int* __restrict__ meta, int* __restrict__ tileMap,
                 int* __restrict__ tokList, float* __restrict__ wList) {
  __shared__ int cnt[NGRP];
  __shared__ int curL[NGRP];
  const int tid = threadIdx.x;            // 1024 threads, 16 items each
  if (tid < NGRP) cnt[tid] = 0;
  __syncthreads();
  int gloc[16];
#pragma unroll
  for (int j = 0; j < 16; ++j) {
    int i = tid + 1024 * j;               // (token,k) flat: k = i&1
    int e = idx[i];
    int g = ((i & 1) << 3) | e;
    gloc[j] = g;
    atomicAdd(&cnt[g], 1);
  }
  __syncthreads();
  if (tid == 0) {
    int run = 0, t = 0, tk0 = 0;
    for (int g = 0; g < NGRP; ++g) {
      curL[g] = run;
      meta[g] = cnt[g];
      meta[16 + g] = run;
      int ntl = (cnt[g] + 127) >> 7;      // tiles of BM=128
      for (int m0 = 0; m0 < ntl; ++m0) tileMap[t++] = (g << 12) | m0;
      if (g == NEXP - 1) tk0 = t;
      run += cnt[g];
    }
    meta[48] = t;
    meta[49] = tk0;
  }
  __syncthreads();
#pragma unroll
  for (int j = 0; j < 16; ++j) {
    int i = tid + 1024 * j;
    int pos = atomicAdd(&curL[gloc[j]], 1);
    tokList[pos] = i >> 1;
    wList[pos] = ew[i];
  }
}

// ---------- conversions ----------
__global__ void convert_x_kernel(const float* __restrict__ x, u16* __restrict__ xb) {
  size_t i = (size_t)blockIdx.x * 256 + threadIdx.x;   // one 8-elem chunk
  const float4* s = reinterpret_cast<const float4*>(x) + 2 * i;
  float4 a = s[0], b = s[1];
  uint4 o;
  o.x = (u32)f2bf(a.x) | ((u32)f2bf(a.y) << 16);
  o.y = (u32)f2bf(a.z) | ((u32)f2bf(a.w) << 16);
  o.z = (u32)f2bf(b.x) | ((u32)f2bf(b.y) << 16);
  o.w = (u32)f2bf(b.z) | ((u32)f2bf(b.w) << 16);
  reinterpret_cast<uint4*>(xb)[i] = o;
}

// W[e][d][f] fp32 -> Wt[e][f][d] bf16 (LDS-tiled transpose)
__global__ void transpose_w_kernel(const float* __restrict__ W, u16* __restrict__ wt) {
  __shared__ u16 tile[32][33];
  const int e = blockIdx.z;
  const int f0 = blockIdx.x * 32, d0 = blockIdx.y * 32;
  const float* src = W + ((size_t)e << 20);
  u16* dst = wt + ((size_t)e << 20);
  const int tx = threadIdx.x, ty = threadIdx.y;   // 32 x 8
#pragma unroll
  for (int j = 0; j < 4; ++j) {
    int d = d0 + ty + 8 * j;
    tile[ty + 8 * j][tx] = f2bf(src[(size_t)d * DIM + f0 + tx]);
  }
  __syncthreads();
#pragma unroll
  for (int j = 0; j < 4; ++j) {
    int f = f0 + ty + 8 * j;
    dst[(size_t)f * DIM + d0 + tx] = tile[tx][ty + 8 * j];
  }
}

// ---------- fused grouped GEMM, 128x128x64, double-buffered 2-phase ----------
// pass = -1 : all 16 groups, k=0 -> out (store), k=1 -> cbuf (store); combine later.
// pass = 0  : k=0 groups, store to out.   pass = 1 : k=1 groups, out += (RMW).
__global__ __launch_bounds__(256, 2)
void moe_gemm_kernel(const u16* __restrict__ xb, const u16* __restrict__ wt,
                     const float* __restrict__ bias, const int* __restrict__ tokList,
                     const float* __restrict__ wList, const int* __restrict__ meta,
                     const int* __restrict__ tileMap, float* __restrict__ out,
                     float* __restrict__ cbuf, int pass) {
  constexpr int BM = 128, BN = 128, BK = 64;
  // XCD-bijective swizzle: nwg = gridDim.y*8 (divisible by 8 by construction)
  const int chunk = gridDim.y;
  int lin = blockIdx.y * 8 + blockIdx.x;
  int swz = (lin & 7) * chunk + (lin >> 3);
  int tileIdx = swz >> 3, nt = swz & 7;

  int tBase = 0, tEnd = meta[48];
  const int tilesK0 = meta[49];
  if (pass == 0) tEnd = tilesK0;
  else if (pass == 1) tBase = tilesK0;
  tileIdx += tBase;
  if (tileIdx >= tEnd) return;

  const int tm = tileMap[tileIdx];
  const int g = tm >> 12, m0 = tm & 0xfff;
  const int e = g & (NEXP - 1);
  const int nrem = meta[g] - m0 * BM;          // rows remaining in group (>0)
  const int listBase = meta[16 + g] + m0 * BM;

  __shared__ __align__(16) u16 As[2][BM * BK];   // 2 x 16KB
  __shared__ __align__(16) u16 Bs[2][BN * BK];   // 2 x 16KB
  __shared__ int   tokS[BM];
  __shared__ float wS[BM];

  const int tid = threadIdx.x;
  if (tid < BM) {
    int pc = tid < nrem ? tid : (nrem - 1);    // clamp ragged tail (masked on store)
    tokS[tid] = tokList[listBase + pc];
    wS[tid]   = wList[listBase + pc];
  }
  __syncthreads();

  const int rowA = tid >> 3;    // 0..31 (stride 32 over 4 rounds)
  const int chnk = tid & 7;     // 16B chunk in a 128B row
  const u16* wb = wt + ((size_t)e << 20);

  const u16* aSrc[4];
  const u16* bSrc[4];
  int dOff[4];
#pragma unroll
  for (int r = 0; r < 4; ++r) {
    int row = rowA + 32 * r;
    aSrc[r] = xb + ((size_t)tokS[row] << 10) + chnk * 8;
    bSrc[r] = wb + ((size_t)(nt * BN + row) << 10) + chnk * 8;
    dOff[r] = row * BK + chnk * 8;
  }

  const int wid = tid >> 6, lane = tid & 63;
  const int wm = (wid >> 1) * 64, wn = (wid & 1) * 64;   // 2x2 waves, 64x64 each
  const int lr = lane & 15, lg = lane >> 4;

  floatx4 acc[4][4];
#pragma unroll
  for (int i = 0; i < 4; ++i)
#pragma unroll
    for (int j = 0; j < 4; ++j) acc[i][j] = (floatx4){0.f, 0.f, 0.f, 0.f};

  // prologue: stage tile 0 into buffer 0
#pragma unroll
  for (int r = 0; r < 4; ++r) {
    gload_lds16(aSrc[r], &As[0][dOff[r]]);
    gload_lds16(bSrc[r], &Bs[0][dOff[r]]);
  }
  asm volatile("s_waitcnt vmcnt(0)" ::: "memory");
  __syncthreads();

  int cur = 0;
  for (int kt = 0; kt < DIM / BK; ++kt) {
    if (kt < DIM / BK - 1) {                 // prefetch next K-tile into buf^1
      const int koff = (kt + 1) * BK;
#pragma unroll
      for (int r = 0; r < 4; ++r) {
        gload_lds16(aSrc[r] + koff, &As[cur ^ 1][dOff[r]]);
        gload_lds16(bSrc[r] + koff, &Bs[cur ^ 1][dOff[r]]);
      }
    }
#pragma unroll
    for (int ks = 0; ks < 2; ++ks) {         // compute current buffer
      bf16x8 av[4], bv[4];
#pragma unroll
      for (int mi = 0; mi < 4; ++mi)
        av[mi] = *reinterpret_cast<const bf16x8*>(&As[cur][(wm + mi * 16 + lr) * BK + ks * 32 + lg * 8]);
#pragma unroll
      for (int ni = 0; ni < 4; ++ni)
        bv[ni] = *reinterpret_cast<const bf16x8*>(&Bs[cur][(wn + ni * 16 + lr) * BK + ks * 32 + lg * 8]);
#pragma unroll
      for (int mi = 0; mi < 4; ++mi)
#pragma unroll
        for (int ni = 0; ni < 4; ++ni)
          acc[mi][ni] = __builtin_amdgcn_mfma_f32_16x16x32_bf16(av[mi], bv[ni], acc[mi][ni], 0, 0, 0);
    }
    asm volatile("s_waitcnt vmcnt(0)" ::: "memory");  // next-buf loads landed
    __syncthreads();                                   // all waves done reading cur
    cur ^= 1;
  }

  // epilogue: D[row=(lane>>4)*4+r][col=lane&15] per 16x16 frag
  float* dst = (pass >= 0 || g < NEXP) ? out : cbuf;
  const bool rmw = (pass == 1);
  const float* bp = bias + e * DIM;
#pragma unroll
  for (int mi = 0; mi < 4; ++mi) {
    const int rl0 = wm + mi * 16 + lg * 4;
#pragma unroll
    for (int ni = 0; ni < 4; ++ni) {
      const int col = nt * BN + wn + ni * 16 + lr;
      const float bv = bp[col];
#pragma unroll
      for (int r = 0; r < 4; ++r) {
        const int rl = rl0 + r;
        if (rl < nrem) {
          const float v = wS[rl] * (acc[mi][ni][r] + bv);
          float* o = dst + ((size_t)tokS[rl] << 10) + col;
          if (rmw) *o += v; else *o = v;
        }
      }
    }
  }
}

// out += cbuf (mode A). 8.4M floats = 2.1M float4.
__global__ void combine_kernel(float* __restrict__ out, const float* __restrict__ cbuf) {
  constexpr int TOTAL4 = TOK * DIM / 4;
  int i = blockIdx.x * 256 + threadIdx.x;
#pragma unroll
  for (int j = 0; j < 4; ++j) {
    int p = i + j * (TOTAL4 / 4);
    float4 a = reinterpret_cast<float4*>(out)[p];
    float4 b = reinterpret_cast<const float4*>(cbuf)[p];
    a.x += b.x; a.y += b.y; a.z += b.z; a.w += b.w;
    reinterpret_cast<float4*>(out)[p] = a;
  }
}

// ---------- host ----------
extern "C" void kernel_launch(void* const* d_in, const int* in_sizes, int n_in,
                              void* d_out, int out_size, void* d_ws, size_t ws_size,
                              hipStream_t stream) {
  const float* x    = (const float*)d_in[0];   // [2,4096,1024] f32
  const float* ew   = (const float*)d_in[1];   // [2,4096,2]    f32
  const int*   idx  = (const int*)d_in[2];     // [2,4096,2]    i32
  const float* W    = (const float*)d_in[3];   // [8,1024,1024] f32
  const float* bias = (const float*)d_in[4];   // [8,1024]      f32
  float* out = (float*)d_out;                  // [2,4096,1024] f32

  char* ws = (char*)d_ws;
  u16*   xb      = (u16*)ws;                                        // 16 MB
  u16*   wtp     = (u16*)(ws + (size_t)(16 << 20));                 // 16 MB
  int*   tokList = (int*)(ws + (size_t)(32 << 20));                 // 64 KB
  float* wList   = (float*)(ws + (size_t)(32 << 20) + (64 << 10));  // 64 KB
  int*   meta    = (int*)(ws + (size_t)(32 << 20) + (128 << 10));   // 64 ints
  int*   tileMap = (int*)(ws + (size_t)(32 << 20) + (129 << 10));   // 144 ints
  float* cbuf    = (float*)(ws + (size_t)(33 << 20));               // 32 MB (mode A)

  const size_t needB = (size_t)(33 << 20);
  const size_t needA = (size_t)(65 << 20);
  if (ws_size < needB) {
    fprintf(stderr, "kernel_launch: ws_size %zu < needed %zu\n", ws_size, needB);
    return;
  }
  const bool modeA = (ws_size >= needA);

  prep_kernel<<<1, 1024, 0, stream>>>(idx, ew, meta, tileMap, tokList, wList);
  convert_x_kernel<<<4096, 256, 0, stream>>>(x, xb);
  transpose_w_kernel<<<dim3(32, 32, 8), dim3(32, 8), 0, stream>>>(W, wtp);

  if (modeA) {
    moe_gemm_kernel<<<dim3(8, 144), 256, 0, stream>>>(
        xb, wtp, bias, tokList, wList, meta, tileMap, out, cbuf, -1);
    combine_kernel<<<TOK * DIM / 4 / 4 / 256, 256, 0, stream>>>(out, cbuf);
  } else {
    moe_gemm_kernel<<<dim3(8, 72), 256, 0, stream>>>(
        xb, wtp, bias, tokList, wList, meta, tileMap, out, nullptr, 0);
    moe_gemm_kernel<<<dim3(8, 72), 256, 0, stream>>>(
        xb, wtp, bias, tokList, wList, meta, tileMap, out, nullptr, 1);
  }
}

// Round 4
// 137.095 us; speedup vs baseline: 1.8863x; 1.1710x over previous
//
#include <hip/hip_runtime.h>
#include <hip/hip_bf16.h>
#include <cstdio>
#include <cstdint>

// Problem constants (B=2, S=4096, D=1024, E=8, K=2)
static constexpr int TOK = 8192;    // B*S tokens
static constexpr int DIM = 1024;    // model dim (in = out)
static constexpr int NEXP = 8;
static constexpr int NGRP = 16;     // (k, expert) groups
static constexpr int ROWS = TOK * 2;  // 16384 gathered rows

typedef unsigned short u16;
typedef unsigned int u32;

using floatx4 = __attribute__((ext_vector_type(4))) float;
using bf16x8  = __attribute__((ext_vector_type(8))) __bf16;

// meta (ints): [0..15] counts, [16..31] offsets, [48] numTiles, [49] numTiles k=0
// tileMap: up to 144 ints, (g<<12)|m0

// ---------- helpers ----------
__device__ __forceinline__ u16 f2bf(float f) {
  union { float f; u32 u; } v; v.f = f;
  u32 r = v.u + 0x7fffu + ((v.u >> 16) & 1u);   // RNE
  return (u16)(r >> 16);
}

__device__ __forceinline__ float bf2f(u16 b) {
  union { u32 u; float f; } v; v.u = (u32)b << 16;
  return v.f;
}

__device__ __forceinline__ void gload_lds16(const void* g, void* l) {
  __builtin_amdgcn_global_load_lds(
      (const __attribute__((address_space(1))) void*)g,
      (__attribute__((address_space(3))) void*)l,
      16, 0, 0);
}

// ---------- fused bookkeeping: count + scan + tileMap + scatter, one block ----------
__global__ __launch_bounds__(1024)
void prep_kernel(const int* __restrict__ idx, const float* __restrict__ ew,
                 int* __restrict__ meta, int* __restrict__ tileMap,
                 int* __restrict__ tokList, float* __restrict__ wList) {
  __shared__ int cnt[NGRP];
  __shared__ int curL[NGRP];
  const int tid = threadIdx.x;            // 1024 threads, 16 items each
  if (tid < NGRP) cnt[tid] = 0;
  __syncthreads();
  int gloc[16];
#pragma unroll
  for (int j = 0; j < 16; ++j) {
    int i = tid + 1024 * j;               // (token,k) flat: k = i&1
    int e = idx[i];
    int g = ((i & 1) << 3) | e;
    gloc[j] = g;
    atomicAdd(&cnt[g], 1);
  }
  __syncthreads();
  if (tid == 0) {
    int run = 0, t = 0, tk0 = 0;
    for (int g = 0; g < NGRP; ++g) {
      curL[g] = run;
      meta[g] = cnt[g];
      meta[16 + g] = run;
      int ntl = (cnt[g] + 127) >> 7;      // tiles of BM=128
      for (int m0 = 0; m0 < ntl; ++m0) tileMap[t++] = (g << 12) | m0;
      if (g == NEXP - 1) tk0 = t;
      run += cnt[g];
    }
    meta[48] = t;
    meta[49] = tk0;
  }
  __syncthreads();
#pragma unroll
  for (int j = 0; j < 16; ++j) {
    int i = tid + 1024 * j;
    int pos = atomicAdd(&curL[gloc[j]], 1);
    tokList[pos] = i >> 1;
    wList[pos] = ew[i];
  }
}

// ---------- gather + convert: Abuf[pos][:] = bf16(x[tokList[pos]][:]) ----------
// One block per row; fully coalesced read (float4) and write (bf16x4 = 8B).
__global__ __launch_bounds__(256)
void gather_x_kernel(const float* __restrict__ x, const int* __restrict__ tokList,
                     u16* __restrict__ Abuf) {
  const int row = blockIdx.x;
  const int tok = tokList[row];
  const int tid = threadIdx.x;
  float4 v = reinterpret_cast<const float4*>(x + ((size_t)tok << 10))[tid];
  ushort4 o;
  o.x = f2bf(v.x); o.y = f2bf(v.y); o.z = f2bf(v.z); o.w = f2bf(v.w);
  reinterpret_cast<ushort4*>(Abuf + ((size_t)row << 10))[tid] = o;
}

// W[e][d][f] fp32 -> Wt[e][f][d] bf16 (LDS-tiled transpose)
__global__ void transpose_w_kernel(const float* __restrict__ W, u16* __restrict__ wt) {
  __shared__ u16 tile[32][33];
  const int e = blockIdx.z;
  const int f0 = blockIdx.x * 32, d0 = blockIdx.y * 32;
  const float* src = W + ((size_t)e << 20);
  u16* dst = wt + ((size_t)e << 20);
  const int tx = threadIdx.x, ty = threadIdx.y;   // 32 x 8
#pragma unroll
  for (int j = 0; j < 4; ++j) {
    int d = d0 + ty + 8 * j;
    tile[ty + 8 * j][tx] = f2bf(src[(size_t)d * DIM + f0 + tx]);
  }
  __syncthreads();
#pragma unroll
  for (int j = 0; j < 4; ++j) {
    int f = f0 + ty + 8 * j;
    dst[(size_t)f * DIM + d0 + tx] = tile[tx][ty + 8 * j];
  }
}

// ---------- fused grouped GEMM, 128x128x64, single-buffer serial (r2 structure) ----------
// pass = -1 : all 16 groups; k=0 -> out (fp32 store), k=1 -> cbuf16 (bf16 store).
// pass = 0  : k=0 groups, store to out.   pass = 1 : k=1 groups, out += (RMW).
__global__ __launch_bounds__(256)
void moe_gemm_kernel(const u16* __restrict__ Abuf, const u16* __restrict__ wt,
                     const float* __restrict__ bias, const int* __restrict__ tokList,
                     const float* __restrict__ wList, const int* __restrict__ meta,
                     const int* __restrict__ tileMap, float* __restrict__ out,
                     u16* __restrict__ cbuf, int pass) {
  constexpr int BM = 128, BN = 128, BK = 64;
  // XCD mapping: nt == XCD id -> per-XCD B working set = 2 MB (L2-resident)
  const int chunk = gridDim.y;
  int lin = blockIdx.y * 8 + blockIdx.x;
  int swz = (lin & 7) * chunk + (lin >> 3);
  int tileIdx = swz >> 3, nt = swz & 7;

  int tBase = 0, tEnd = meta[48];
  const int tilesK0 = meta[49];
  if (pass == 0) tEnd = tilesK0;
  else if (pass == 1) tBase = tilesK0;
  tileIdx += tBase;
  if (tileIdx >= tEnd) return;

  const int tm = tileMap[tileIdx];
  const int g = tm >> 12, m0 = tm & 0xfff;
  const int e = g & (NEXP - 1);
  const int nrem = meta[g] - m0 * BM;          // rows remaining in group (>0)
  const int listBase = meta[16 + g] + m0 * BM;

  __shared__ __align__(16) u16 As[BM * BK];    // 16KB
  __shared__ __align__(16) u16 Bs[BN * BK];    // 16KB

  const int tid = threadIdx.x;
  const int rowA = tid >> 3;    // 0..31 (stride 32 over 4 rounds)
  const int chnk = tid & 7;     // 16B chunk in a 128B row
  const u16* wb = wt + ((size_t)e << 20);
  const u16* ab = Abuf + ((size_t)listBase << 10);   // contiguous sorted rows

  const int wid = tid >> 6, lane = tid & 63;
  const int wm = (wid >> 1) * 64, wn = (wid & 1) * 64;   // 2x2 waves, 64x64 each
  const int lr = lane & 15, lg = lane >> 4;

  floatx4 acc[4][4];
#pragma unroll
  for (int i = 0; i < 4; ++i)
#pragma unroll
    for (int j = 0; j < 4; ++j) acc[i][j] = (floatx4){0.f, 0.f, 0.f, 0.f};

  for (int kt = 0; kt < DIM / BK; ++kt) {
    __syncthreads();                      // previous tile fully consumed
#pragma unroll
    for (int r = 0; r < 4; ++r) {         // A: contiguous rows of Abuf
      const int row = rowA + 32 * r;
      gload_lds16(ab + ((size_t)row << 10) + kt * BK + chnk * 8,
                  &As[row * BK + chnk * 8]);
    }
#pragma unroll
    for (int r = 0; r < 4; ++r) {         // B: Wt rows (f-major, d-contiguous)
      const int row = rowA + 32 * r;
      gload_lds16(wb + ((size_t)(nt * BN + row) << 10) + kt * BK + chnk * 8,
                  &Bs[row * BK + chnk * 8]);
    }
    asm volatile("s_waitcnt vmcnt(0)" ::: "memory");
    __syncthreads();

#pragma unroll
    for (int ks = 0; ks < 2; ++ks) {      // two K=32 sub-steps
      bf16x8 av[4], bv[4];
#pragma unroll
      for (int mi = 0; mi < 4; ++mi)
        av[mi] = *reinterpret_cast<const bf16x8*>(&As[(wm + mi * 16 + lr) * BK + ks * 32 + lg * 8]);
#pragma unroll
      for (int ni = 0; ni < 4; ++ni)
        bv[ni] = *reinterpret_cast<const bf16x8*>(&Bs[(wn + ni * 16 + lr) * BK + ks * 32 + lg * 8]);
#pragma unroll
      for (int mi = 0; mi < 4; ++mi)
#pragma unroll
        for (int ni = 0; ni < 4; ++ni)
          acc[mi][ni] = __builtin_amdgcn_mfma_f32_16x16x32_bf16(av[mi], bv[ni], acc[mi][ni], 0, 0, 0);
    }
  }

  // epilogue: D[row=(lane>>4)*4+r][col=lane&15] per 16x16 frag
  const bool toCbuf = (pass < 0) && (g >= NEXP);
  const bool rmw = (pass == 1);
  const float* bp = bias + e * DIM;
#pragma unroll
  for (int mi = 0; mi < 4; ++mi) {
#pragma unroll
    for (int r = 0; r < 4; ++r) {
      const int rl = wm + mi * 16 + lg * 4 + r;
      if (rl < nrem) {
        const int   tok = tokList[listBase + rl];
        const float w   = wList[listBase + rl];
        const size_t rowOff = (size_t)tok << 10;
#pragma unroll
        for (int ni = 0; ni < 4; ++ni) {
          const int col = nt * BN + wn + ni * 16 + lr;
          const float v = w * (acc[mi][ni][r] + bp[col]);
          if (toCbuf)      cbuf[rowOff + col] = f2bf(v);
          else if (rmw)    out[rowOff + col] += v;
          else             out[rowOff + col] = v;
        }
      }
    }
  }
}

// out += cbuf(bf16). 8.4M elems, 8 per thread.
__global__ __launch_bounds__(256)
void combine_kernel(float* __restrict__ out, const u16* __restrict__ cbuf) {
  const int p = blockIdx.x * 256 + threadIdx.x;   // 8-elem chunk index
  uint4 c = reinterpret_cast<const uint4*>(cbuf)[p];
  float4* o4 = reinterpret_cast<float4*>(out) + 2 * (size_t)p;
  float4 a = o4[0], b = o4[1];
  a.x += bf2f((u16)(c.x & 0xffff)); a.y += bf2f((u16)(c.x >> 16));
  a.z += bf2f((u16)(c.y & 0xffff)); a.w += bf2f((u16)(c.y >> 16));
  b.x += bf2f((u16)(c.z & 0xffff)); b.y += bf2f((u16)(c.z >> 16));
  b.z += bf2f((u16)(c.w & 0xffff)); b.w += bf2f((u16)(c.w >> 16));
  o4[0] = a; o4[1] = b;
}

// ---------- host ----------
extern "C" void kernel_launch(void* const* d_in, const int* in_sizes, int n_in,
                              void* d_out, int out_size, void* d_ws, size_t ws_size,
                              hipStream_t stream) {
  const float* x    = (const float*)d_in[0];   // [2,4096,1024] f32
  const float* ew   = (const float*)d_in[1];   // [2,4096,2]    f32
  const int*   idx  = (const int*)d_in[2];     // [2,4096,2]    i32
  const float* W    = (const float*)d_in[3];   // [8,1024,1024] f32
  const float* bias = (const float*)d_in[4];   // [8,1024]      f32
  float* out = (float*)d_out;                  // [2,4096,1024] f32

  char* ws = (char*)d_ws;
  u16*   Abuf = (u16*)ws;                                  // 32 MB sorted bf16 rows
  u16*   wtp  = (u16*)(ws + ((size_t)32 << 20));           // 16 MB bf16 W^T
  u16*   cbuf = (u16*)(ws + ((size_t)48 << 20));           // 16 MB bf16 k=1 partials (mode A)

  const size_t needB = ((size_t)48 << 20) + (132 << 10);   // no cbuf
  const size_t needA = ((size_t)64 << 20) + (132 << 10);   // with cbuf
  if (ws_size < needB) {
    fprintf(stderr, "kernel_launch: ws_size %zu < needed %zu\n", ws_size, needB);
    return;
  }
  const bool modeA = (ws_size >= needA);
  char* tail = ws + (modeA ? ((size_t)64 << 20) : ((size_t)48 << 20));
  int*   tokList = (int*)tail;                  // 64 KB
  float* wList   = (float*)(tail + (64 << 10)); // 64 KB
  int*   meta    = (int*)(tail + (128 << 10));  // 64 ints
  int*   tileMap = (int*)(tail + (129 << 10));  // 144 ints

  prep_kernel<<<1, 1024, 0, stream>>>(idx, ew, meta, tileMap, tokList, wList);
  gather_x_kernel<<<ROWS, 256, 0, stream>>>(x, tokList, Abuf);
  transpose_w_kernel<<<dim3(32, 32, 8), dim3(32, 8), 0, stream>>>(W, wtp);

  if (modeA) {
    moe_gemm_kernel<<<dim3(8, 144), 256, 0, stream>>>(
        Abuf, wtp, bias, tokList, wList, meta, tileMap, out, cbuf, -1);
    combine_kernel<<<TOK * DIM / 8 / 256, 256, 0, stream>>>(out, cbuf);
  } else {
    moe_gemm_kernel<<<dim3(8, 72), 256, 0, stream>>>(
        Abuf, wtp, bias, tokList, wList, meta, tileMap, out, nullptr, 0);
    moe_gemm_kernel<<<dim3(8, 72), 256, 0, stream>>>(
        Abuf, wtp, bias, tokList, wList, meta, tileMap, out, nullptr, 1);
  }
}